// Round 10
// baseline (410.735 us; speedup 1.0000x reference)
//
#include <hip/hip_runtime.h>

#define BB 4
#define NT 256
#define NZ 384
#define NX 384
#define NREC 128
#define NZX (NZ*NX)        // 147456
#define BNZX (BB*NZX)      // 589824
#define DT 0.001f
#define INV_DH2 0.01f      // 1/(10*10)

#define TZN 24             // interior tile rows
#define TXN 48             // interior tile cols
#define HALO 8             // halo width = steps per exchange
#define RZN 40             // TZN + 2*HALO
#define RXN 64             // TXN + 2*HALO (= lane count)
#define NTBZ 16            // tiles in z per batch
#define NTBX 8             // tiles in x per batch
#define NBLK 512           // 16*8*4  -> 2 blocks/CU co-resident
#define NWAVE 5            // wave w owns rows 8w..8w+7, lane = col
#define NTHR (NWAVE*64)    // 320
#define FSTRIDE 16         // flag spread (64 B)

__global__ void wave_init(unsigned* flags) {
    int i = blockIdx.x * blockDim.x + threadIdx.x;
    if (i < NBLK * FSTRIDE) flags[i] = 0u;
}

__device__ inline float dpp_shl1(float v) {
    return __int_as_float(__builtin_amdgcn_update_dpp(
        0, __float_as_int(v), 0x130 /*WAVE_SHL1*/, 0xf, 0xf, true));
}
__device__ inline float dpp_shr1(float v) {
    return __int_as_float(__builtin_amdgcn_update_dpp(
        0, __float_as_int(v), 0x138 /*WAVE_SHR1*/, 0xf, 0xf, true));
}
// agent-scope relaxed ops: coherent at LLC, no cache-maintenance instructions
__device__ inline float ldgf(const float* p) {
    return __hip_atomic_load(p, __ATOMIC_RELAXED, __HIP_MEMORY_SCOPE_AGENT);
}
__device__ inline void stgf(float* p, float v) {
    __hip_atomic_store(p, v, __ATOMIC_RELAXED, __HIP_MEMORY_SCOPE_AGENT);
}
__device__ inline unsigned ldflag(const unsigned* p) {
    return __hip_atomic_load(p, __ATOMIC_RELAXED, __HIP_MEMORY_SCOPE_AGENT);
}

__global__ __launch_bounds__(NTHR)
void wave_tiled(float* __restrict__ ws, const float* __restrict__ vp,
                const float* __restrict__ x,
                const int* __restrict__ src_y, const int* __restrict__ src_x,
                const int* __restrict__ rec_y, const int* __restrict__ rec_x,
                float* __restrict__ y) {
    __shared__ float bnd[2][2*NWAVE][RXN];  // [parity][2*wave+{top,bot}][col]
    __shared__ float recBuf[NREC][8];
    __shared__ float xs[NT];
    __shared__ int recLoc[NREC], recOut[NREC];
    __shared__ int recCnt;

    unsigned* flags = (unsigned*)(ws + 4*BNZX);
    float* F0 = ws;            // parity-0 frames: cur, prv
    float* F1 = ws + 2*BNZX;   // parity-1 frames

    const int tid = threadIdx.x;
    const int col = tid & 63;
    const int w   = tid >> 6;
    const int r0  = w << 3;
    const int blk = blockIdx.x;
    const int b  = blk >> 7;
    const int tz = (blk >> 3) & 15;
    const int tx = blk & 7;
    const int oz = tz*TZN - HALO, ox = tx*TXN - HALO;
    const int gx = ox + col;
    const int sy = src_y[b], sx = src_x[b];

    if (tid == 0) recCnt = 0;
    for (int k = tid; k < 2*2*NWAVE*RXN; k += NTHR) ((float*)bnd)[k] = 0.f;
    for (int k = tid; k < NT; k += NTHR) xs[k] = x[b*NT + k];
    __syncthreads();
    for (int r = tid; r < NREC; r += NTHR) {
        int ry = rec_y[r], rx = rec_x[r];
        if (ry/TZN == tz && rx/TXN == tx) {
            int p = atomicAdd(&recCnt, 1);
            recLoc[p] = ((ry - oz) << 6) | (rx - ox);
            recOut[p] = b*NREC + r;
        }
    }
    __syncthreads();

    // per-thread receiver ownership cache (cap 4, scan fallback)
    int myN = 0, myM[4], myP[4];
    bool ovf = false;
    for (int p = 0; p < recCnt; ++p) {
        int rl = recLoc[p];
        if ((rl & 63) == col) {
            int rm = (rl >> 6) - r0;
            if ((unsigned)rm < 8u) {
                if (myN < 4) { myM[myN] = rm; myP[myN] = p; ++myN; }
                else ovf = true;
            }
        }
    }

    // neighbor block ids for the sync (lanes 0..7 of wave 0; others self)
    int nbId = blk;
    if (tid < 8) {
        int d = tid + (tid >= 4);            // 0..8 skipping center
        int nz2 = tz + d/3 - 1, nx2 = tx + d%3 - 1;
        if ((unsigned)nz2 < (unsigned)NTBZ && (unsigned)nx2 < (unsigned)NTBX)
            nbId = (b << 7) | (nz2 << 3) | nx2;
    }

    float cur[8], prv[8], c2i[8];
    #pragma unroll
    for (int m = 0; m < 8; ++m) {
        cur[m] = 0.f; prv[m] = 0.f;
        const int gz = oz + r0 + m;
        const bool inner = (gz > 0 && gz < NZ-1 && gx > 0 && gx < NX-1);
        const float v = inner ? vp[gz*NX + gx] * DT : 0.f;
        c2i[m] = v * v * INV_DH2;    // 0 at edges -> lap auto-masked
    }
    const bool srcCol = (gx == sx);
    const int  srcM   = sy - oz - r0;
    const int  iuUp   = (2*w-1 < 0) ? 0 : 2*w-1;
    const int  iuDn   = (2*w+2 > 2*NWAVE-1) ? 2*NWAVE-1 : 2*w+2;
    const bool gxIn   = (gx >= 0 && gx < NX);
    const int  gxc    = min(max(gx, 0), NX-1);
    __syncthreads();

    #pragma unroll 1
    for (int t = 0; t < NT; ++t) {
        const int pr = t & 1, pw = pr ^ 1;
        const float upB = bnd[pr][iuUp][col];
        const float dnB = bnd[pr][iuDn][col];

        float hn[8];
        #pragma unroll
        for (int m = 0; m < 8; ++m) {
            const float ce = cur[m];
            const float up = (m == 0) ? upB : cur[m-1];
            const float dn = (m == 7) ? dnB : cur[m+1];
            const float lf = dpp_shl1(ce);
            const float rt = dpp_shr1(ce);
            const float s  = (up + dn) + (lf + rt);
            hn[m] = fmaf(2.f, ce, -prv[m]) + c2i[m] * fmaf(-4.f, ce, s);
        }
        #pragma unroll
        for (int m = 0; m < 8; ++m) { prv[m] = cur[m]; cur[m] = hn[m]; }

        if (srcCol && (unsigned)srcM < 8u) {
            const float xv = xs[t];
            #pragma unroll
            for (int m = 0; m < 8; ++m) if (m == srcM) cur[m] += xv;
        }
        {   // receiver sampling -> LDS (no global ops in step loop)
            const int s2 = t & 7;
            if (ovf) {
                for (int p = 0; p < recCnt; ++p) {
                    int rl = recLoc[p];
                    if ((rl & 63) == col) {
                        int rm = (rl >> 6) - r0;
                        if ((unsigned)rm < 8u) {
                            float v = cur[0];
                            #pragma unroll
                            for (int m = 1; m < 8; ++m) if (rm == m) v = cur[m];
                            recBuf[p][s2] = v;
                        }
                    }
                }
            } else {
                #pragma unroll
                for (int k = 0; k < 4; ++k) {
                    if (k < myN) {
                        float v = cur[0];
                        #pragma unroll
                        for (int m = 1; m < 8; ++m) if (myM[k] == m) v = cur[m];
                        recBuf[myP[k]][s2] = v;
                    }
                }
            }
        }
        bnd[pw][2*w  ][col] = cur[0];
        bnd[pw][2*w+1][col] = cur[7];

        if ((t & 7) == 7) {
            const int o = t >> 3;
            if (t < NT-1) {
                // frame stores straight from registers (before the drain sync)
                float* Gc = (o & 1) ? F1 : F0;
                float* Gp = Gc + BNZX;
                const bool colF = (col >= HALO   && col < RXN-HALO);
                const bool colM = (col >= 2*HALO && col < RXN-2*HALO);
                #pragma unroll
                for (int m = 0; m < 8; ++m) {
                    const int i = r0 + m;
                    const bool rowF = (i >= HALO   && i < RZN-HALO);
                    const bool rowM = (i >= 2*HALO && i < RZN-2*HALO);
                    if (colF && rowF && !(colM && rowM)) {
                        const size_t g = (size_t)b*NZX + (size_t)(oz+i)*NX + gx;
                        stgf(&Gc[g], cur[m]);
                        stgf(&Gp[g], prv[m]);
                    }
                }
                __syncthreads();  // per-wave vmcnt(0) drains + recBuf visible
                if (tid < 64) {   // wave 0: arrive + hard-spin on <=8 neighbors
                    if (tid == 0)
                        __hip_atomic_store(&flags[blk * FSTRIDE], (unsigned)(o+1),
                                           __ATOMIC_RELAXED, __HIP_MEMORY_SCOPE_AGENT);
                    for (;;) {
                        unsigned f = ldflag(&flags[nbId * FSTRIDE]);
                        if (__all(f >= (unsigned)(o+1))) break;
                    }
                } else {          // waves 1..4: flush y concurrently with poll
                    for (int k = tid - 64; k < recCnt*8; k += NTHR - 64) {
                        int p = k >> 3, s2 = k & 7;
                        y[(size_t)((o<<3)+s2)*(BB*NREC) + recOut[p]] = recBuf[p][s2];
                    }
                }
                __syncthreads();
                // ring reload: issue ALL loads, then use (single waitcnt)
                const bool colH = (col < HALO || col >= RXN-HALO);
                float tc[8], tp[8];
                bool ringm[8], valm[8];
                #pragma unroll
                for (int m = 0; m < 8; ++m) {
                    const int i = r0 + m;
                    const int gz = oz + i;
                    ringm[m] = colH || i < HALO || i >= RZN-HALO;
                    valm[m]  = gxIn && gz >= 0 && gz < NZ;
                    const int gzc = min(max(gz, 0), NZ-1);
                    if (ringm[m]) {
                        const size_t g = (size_t)b*NZX + (size_t)gzc*NX + gxc;
                        tc[m] = ldgf(&Gc[g]);
                        tp[m] = ldgf(&Gp[g]);
                    }
                }
                #pragma unroll
                for (int m = 0; m < 8; ++m) {
                    if (ringm[m]) {
                        cur[m] = valm[m] ? tc[m] : 0.f;
                        prv[m] = valm[m] ? tp[m] : 0.f;
                    }
                }
                bnd[pw][2*w  ][col] = cur[0];
                bnd[pw][2*w+1][col] = cur[7];
            } else {
                // last window: flush y with all threads
                __syncthreads();
                for (int k = tid; k < recCnt*8; k += NTHR) {
                    int p = k >> 3, s2 = k & 7;
                    y[(size_t)((o<<3)+s2)*(BB*NREC) + recOut[p]] = recBuf[p][s2];
                }
            }
        }
        __syncthreads();
    }
}

extern "C" void kernel_launch(void* const* d_in, const int* in_sizes, int n_in,
                              void* d_out, int out_size, void* d_ws, size_t ws_size,
                              hipStream_t stream) {
    const float* x     = (const float*)d_in[0];
    const float* vp    = (const float*)d_in[1];
    const int*   src_y = (const int*)d_in[2];
    const int*   src_x = (const int*)d_in[3];
    const int*   rec_y = (const int*)d_in[4];
    const int*   rec_x = (const int*)d_in[5];
    float* y  = (float*)d_out;
    float* ws = (float*)d_ws;   // 4*BNZX frame floats + 512*16 flag words (~9.5 MB)

    wave_init<<<(NBLK*FSTRIDE + 255)/256, 256, 0, stream>>>((unsigned*)(ws + 4*BNZX));
    wave_tiled<<<NBLK, NTHR, 0, stream>>>(ws, vp, x, src_y, src_x, rec_y, rec_x, y);
}

// Round 11
// 384.528 us; speedup vs baseline: 1.0682x; 1.0682x over previous
//
#include <hip/hip_runtime.h>

#define BB 4
#define NT 256
#define NZ 384
#define NX 384
#define NREC 128
#define NZX (NZ*NX)        // 147456
#define BNZX (BB*NZX)      // 589824
#define DT 0.001f
#define INV_DH2 0.01f      // 1/(10*10)

#define TZN 24             // interior tile rows
#define TXN 48             // interior tile cols
#define HALO 8             // halo width = max steps per exchange window
#define RZN 40             // TZN + 2*HALO
#define RXN 64             // TXN + 2*HALO (= lane count)
#define NTBZ 16            // tiles in z per batch
#define NTBX 8             // tiles in x per batch
#define TPB 128            // tiles per batch
#define NBLK 512           // b*128 + tile  -> 2 blocks/CU, partners = (b, b+2)
#define NWAVE 4
#define ROWS 10            // rows per thread (4*10 = 40 = RZN)
#define NTHR 256
#define FSTRIDE 16         // flag spread (64 B)

__global__ void wave_init(unsigned* flags) {
    int i = blockIdx.x * blockDim.x + threadIdx.x;
    if (i < NBLK * FSTRIDE) flags[i] = 0u;
}

__device__ inline float dpp_shl1(float v) {
    return __int_as_float(__builtin_amdgcn_update_dpp(
        0, __float_as_int(v), 0x130 /*WAVE_SHL1*/, 0xf, 0xf, true));
}
__device__ inline float dpp_shr1(float v) {
    return __int_as_float(__builtin_amdgcn_update_dpp(
        0, __float_as_int(v), 0x138 /*WAVE_SHR1*/, 0xf, 0xf, true));
}
// agent-scope relaxed ops: coherent at LLC, no cache-maintenance instructions
__device__ inline float ldgf(const float* p) {
    return __hip_atomic_load(p, __ATOMIC_RELAXED, __HIP_MEMORY_SCOPE_AGENT);
}
__device__ inline void stgf(float* p, float v) {
    __hip_atomic_store(p, v, __ATOMIC_RELAXED, __HIP_MEMORY_SCOPE_AGENT);
}
__device__ inline unsigned ldflag(const unsigned* p) {
    return __hip_atomic_load(p, __ATOMIC_RELAXED, __HIP_MEMORY_SCOPE_AGENT);
}

__global__ __launch_bounds__(NTHR, 2)
void wave_tiled(float* __restrict__ ws, const float* __restrict__ vp,
                const float* __restrict__ x,
                const int* __restrict__ src_y, const int* __restrict__ src_x,
                const int* __restrict__ rec_y, const int* __restrict__ rec_x,
                float* __restrict__ y) {
    __shared__ float bnd[2][2*NWAVE][RXN];  // [parity][2*wave+{top,bot}][col]
    __shared__ float recBuf[NREC][8];
    __shared__ float xs[NT];
    __shared__ int recLoc[NREC], recOut[NREC];
    __shared__ int recCnt;

    unsigned* flags = (unsigned*)(ws + 4*BNZX);
    float* F0 = ws;            // parity-0 frames: cur, prv
    float* F1 = ws + 2*BNZX;   // parity-1 frames

    const int tid = threadIdx.x;
    const int col = tid & 63;
    const int w   = tid >> 6;
    const int r0  = w * ROWS;
    const int blk = blockIdx.x;
    const int b    = blk >> 7;           // batch-major: co-resident pair = b, b+2
    const int tile = blk & 127;
    const int tz = tile >> 3;            // 0..15
    const int tx = tile & 7;             // 0..7
    const int oz = tz*TZN - HALO, ox = tx*TXN - HALO;
    const int gx = ox + col;
    const int sy = src_y[b], sx = src_x[b];
    const int ph = 2*b;                  // batch phase shift (partners offset 4)

    if (tid == 0) recCnt = 0;
    for (int k = tid; k < 2*2*NWAVE*RXN; k += NTHR) ((float*)bnd)[k] = 0.f;
    for (int k = tid; k < NT; k += NTHR) xs[k] = x[b*NT + k];
    __syncthreads();
    for (int r = tid; r < NREC; r += NTHR) {
        int ry = rec_y[r], rx = rec_x[r];
        if (ry/TZN == tz && rx/TXN == tx) {
            int p = atomicAdd(&recCnt, 1);
            recLoc[p] = ((ry - oz) << 6) | (rx - ox);
            recOut[p] = b*NREC + r;
        }
    }
    __syncthreads();

    // per-thread receiver ownership cache (cap 4, scan fallback)
    int myN = 0, myM[4], myP[4];
    bool ovf = false;
    for (int p = 0; p < recCnt; ++p) {
        int rl = recLoc[p];
        if ((rl & 63) == col) {
            int rm = (rl >> 6) - r0;
            if ((unsigned)rm < (unsigned)ROWS) {
                if (myN < 4) { myM[myN] = rm; myP[myN] = p; ++myN; }
                else ovf = true;
            }
        }
    }
    const bool waveRec = __any(myN > 0 || ovf);   // wave-uniform skip

    // neighbor block ids for the sync (lanes 0..7 of wave 0; others self)
    int nbId = blk;
    if (tid < 8) {
        int d = tid + (tid >= 4);            // 0..8 skipping center
        int nz2 = tz + d/3 - 1, nx2 = tx + d%3 - 1;
        if ((unsigned)nz2 < (unsigned)NTBZ && (unsigned)nx2 < (unsigned)NTBX)
            nbId = (b << 7) | (nz2 << 3) | nx2;
    }

    float cur[ROWS], prv[ROWS], c2i[ROWS];
    #pragma unroll
    for (int m = 0; m < ROWS; ++m) {
        cur[m] = 0.f; prv[m] = 0.f;
        const int gz = oz + r0 + m;
        const bool inner = (gz > 0 && gz < NZ-1 && gx > 0 && gx < NX-1);
        const float v = inner ? vp[gz*NX + gx] * DT : 0.f;
        c2i[m] = v * v * INV_DH2;    // 0 at edges -> lap auto-masked
    }
    const bool srcCol = (gx == sx);
    const int  srcM   = sy - oz - r0;
    const int  iuUp   = (2*w-1 < 0) ? 0 : 2*w-1;
    const int  iuDn   = (2*w+2 > 2*NWAVE-1) ? 2*NWAVE-1 : 2*w+2;
    const bool gxIn   = (gx >= 0 && gx < NX);
    const int  gxc    = min(max(gx, 0), NX-1);
    int oCnt = 0;                       // exchanges completed
    __syncthreads();

    #pragma unroll 1
    for (int t = 0; t < NT; ++t) {
        const int p  = (t + ph) & 7;    // phase within this batch's window
        const int s  = p + 1;           // trapezoid depth this step
        const int pr = t & 1, pw = pr ^ 1;
        const float upB = bnd[pr][iuUp][col];
        const float dnB = bnd[pr][iuDn][col];
        const bool colAct = (col >= s && col < RXN - s);

        float hn[ROWS];
        #pragma unroll
        for (int m = 0; m < ROWS; ++m) {
            const float ce = cur[m];
            const float up = (m == 0) ? upB : cur[m-1];
            const float dn = (m == ROWS-1) ? dnB : cur[m+1];
            const float lf = dpp_shl1(ce);
            const float rt = dpp_shr1(ce);
            const float sm = (up + dn) + (lf + rt);
            hn[m] = fmaf(2.f, ce, -prv[m]) + c2i[m] * fmaf(-4.f, ce, sm);
        }
        #pragma unroll
        for (int m = 0; m < ROWS; ++m) {
            const int i = r0 + m;
            const bool act = colAct && i >= s && i < RZN - s;
            if (act) { prv[m] = cur[m]; cur[m] = hn[m]; }
        }

        if (srcCol && (unsigned)srcM < (unsigned)ROWS) {
            const float xv = xs[t];
            #pragma unroll
            for (int m = 0; m < ROWS; ++m) if (m == srcM) cur[m] += xv;
        }
        if (waveRec) {   // receiver sampling -> LDS (wave-uniform skip)
            if (ovf) {
                for (int q = 0; q < recCnt; ++q) {
                    int rl = recLoc[q];
                    if ((rl & 63) == col) {
                        int rm = (rl >> 6) - r0;
                        if ((unsigned)rm < (unsigned)ROWS) {
                            float v = cur[0];
                            #pragma unroll
                            for (int m = 1; m < ROWS; ++m) if (rm == m) v = cur[m];
                            recBuf[q][p] = v;
                        }
                    }
                }
            } else {
                #pragma unroll
                for (int k = 0; k < 4; ++k) {
                    if (k < myN) {
                        float v = cur[0];
                        #pragma unroll
                        for (int m = 1; m < ROWS; ++m) if (myM[k] == m) v = cur[m];
                        recBuf[myP[k]][p] = v;
                    }
                }
            }
        }
        bnd[pw][2*w  ][col] = cur[0];
        bnd[pw][2*w+1][col] = cur[ROWS-1];

        if (t == NT-1) {
            // final flush: all threads, slots 0..p (tg = t-p+s2)
            __syncthreads();
            for (int k = tid; k < recCnt*8; k += NTHR) {
                int q = k >> 3, s2 = k & 7;
                if (s2 <= p) {
                    int tg = t - p + s2;
                    y[(size_t)tg*(BB*NREC) + recOut[q]] = recBuf[q][s2];
                }
            }
        } else if (p == 7) {
            // ---- window exchange (phase-shifted per batch) ----
            float* Gc = (oCnt & 1) ? F1 : F0;
            float* Gp = Gc + BNZX;
            const bool colF = (col >= HALO   && col < RXN-HALO);
            const bool colM = (col >= 2*HALO && col < RXN-2*HALO);
            #pragma unroll
            for (int m = 0; m < ROWS; ++m) {
                const int i = r0 + m;
                const bool rowF = (i >= HALO   && i < RZN-HALO);
                const bool rowM = (i >= 2*HALO && i < RZN-2*HALO);
                if (colF && rowF && !(colM && rowM)) {
                    const size_t g = (size_t)b*NZX + (size_t)(oz+i)*NX + gx;
                    stgf(&Gc[g], cur[m]);
                    stgf(&Gp[g], prv[m]);
                }
            }
            __syncthreads();  // per-wave vmcnt(0) drains + recBuf visible
            if (tid < 64) {   // wave 0: arrive + hard-spin on <=8 neighbors
                if (tid == 0)
                    __hip_atomic_store(&flags[blk * FSTRIDE], (unsigned)(oCnt+1),
                                       __ATOMIC_RELAXED, __HIP_MEMORY_SCOPE_AGENT);
                for (;;) {
                    unsigned f = ldflag(&flags[nbId * FSTRIDE]);
                    if (__all(f >= (unsigned)(oCnt+1))) break;
                }
            } else {          // waves 1..3: flush y concurrently with the poll
                for (int k = tid - 64; k < recCnt*8; k += NTHR - 64) {
                    int q = k >> 3, s2 = k & 7;
                    int tg = t - 7 + s2;
                    if (tg >= 0)
                        y[(size_t)tg*(BB*NREC) + recOut[q]] = recBuf[q][s2];
                }
            }
            __syncthreads();
            // ring reload: issue ALL loads, then use (single waitcnt)
            const bool colH = (col < HALO || col >= RXN-HALO);
            float tc[ROWS], tp[ROWS];
            bool ringm[ROWS], valm[ROWS];
            #pragma unroll
            for (int m = 0; m < ROWS; ++m) {
                const int i = r0 + m;
                const int gz = oz + i;
                ringm[m] = colH || i < HALO || i >= RZN-HALO;
                valm[m]  = gxIn && gz >= 0 && gz < NZ;
                const int gzc = min(max(gz, 0), NZ-1);
                if (ringm[m]) {
                    const size_t g = (size_t)b*NZX + (size_t)gzc*NX + gxc;
                    tc[m] = ldgf(&Gc[g]);
                    tp[m] = ldgf(&Gp[g]);
                }
            }
            #pragma unroll
            for (int m = 0; m < ROWS; ++m) {
                if (ringm[m]) {
                    cur[m] = valm[m] ? tc[m] : 0.f;
                    prv[m] = valm[m] ? tp[m] : 0.f;
                }
            }
            bnd[pw][2*w  ][col] = cur[0];
            bnd[pw][2*w+1][col] = cur[ROWS-1];
            ++oCnt;
        }
        __syncthreads();
    }
}

extern "C" void kernel_launch(void* const* d_in, const int* in_sizes, int n_in,
                              void* d_out, int out_size, void* d_ws, size_t ws_size,
                              hipStream_t stream) {
    const float* x     = (const float*)d_in[0];
    const float* vp    = (const float*)d_in[1];
    const int*   src_y = (const int*)d_in[2];
    const int*   src_x = (const int*)d_in[3];
    const int*   rec_y = (const int*)d_in[4];
    const int*   rec_x = (const int*)d_in[5];
    float* y  = (float*)d_out;
    float* ws = (float*)d_ws;   // 4*BNZX frame floats + 512*16 flag words (~9.5 MB)

    wave_init<<<(NBLK*FSTRIDE + 255)/256, 256, 0, stream>>>((unsigned*)(ws + 4*BNZX));
    wave_tiled<<<NBLK, NTHR, 0, stream>>>(ws, vp, x, src_y, src_x, rec_y, rec_x, y);
}

// Round 12
// 325.746 us; speedup vs baseline: 1.2609x; 1.1805x over previous
//
#include <hip/hip_runtime.h>

#define BB 4
#define NT 256
#define NZ 384
#define NX 384
#define NREC 128
#define NZX (NZ*NX)        // 147456
#define BNZX (BB*NZX)      // 589824
#define DT 0.001f
#define INV_DH2 0.01f      // 1/(10*10)

#define TZN 24             // interior tile rows
#define TXN 48             // interior tile cols
#define HALO 8             // halo width = steps per exchange window
#define RZN 40             // TZN + 2*HALO
#define RXN 64             // TXN + 2*HALO (= lane count)
#define NTBZ 16
#define NTBX 8
#define NBLK 512           // b*128 + tile; partners on a CU = (b, b+2), phase off 4
#define NWAVE 4
#define ROWS 10            // 4*10 = 40 = RZN
#define NTHR 256
#define FSTRIDE 16

__global__ void wave_init(unsigned* flags) {
    int i = blockIdx.x * blockDim.x + threadIdx.x;
    if (i < NBLK * FSTRIDE) flags[i] = 0u;
}

__device__ inline float dpp_shl1(float v) {
    return __int_as_float(__builtin_amdgcn_update_dpp(
        0, __float_as_int(v), 0x130 /*WAVE_SHL1*/, 0xf, 0xf, true));
}
__device__ inline float dpp_shr1(float v) {
    return __int_as_float(__builtin_amdgcn_update_dpp(
        0, __float_as_int(v), 0x138 /*WAVE_SHR1*/, 0xf, 0xf, true));
}
__device__ inline float ldgf(const float* p) {
    return __hip_atomic_load(p, __ATOMIC_RELAXED, __HIP_MEMORY_SCOPE_AGENT);
}
__device__ inline void stgf(float* p, float v) {
    __hip_atomic_store(p, v, __ATOMIC_RELAXED, __HIP_MEMORY_SCOPE_AGENT);
}
__device__ inline unsigned ldflag(const unsigned* p) {
    return __hip_atomic_load(p, __ATOMIC_RELAXED, __HIP_MEMORY_SCOPE_AGENT);
}

__global__ __launch_bounds__(NTHR, 2)
void wave_tiled(float* __restrict__ ws, const float* __restrict__ vp,
                const float* __restrict__ x,
                const int* __restrict__ src_y, const int* __restrict__ src_x,
                const int* __restrict__ rec_y, const int* __restrict__ rec_x,
                float* __restrict__ y) {
    __shared__ float bnd[2][2*NWAVE][RXN];
    __shared__ float recBuf[NREC][8];
    __shared__ float xs[NT];
    __shared__ int recLoc[NREC], recOut[NREC];
    __shared__ int recCnt;

    unsigned* flags = (unsigned*)(ws + 4*BNZX);
    float* F0 = ws;
    float* F1 = ws + 2*BNZX;

    const int tid = threadIdx.x;
    const int col = tid & 63;
    const int w   = tid >> 6;
    const int r0  = w * ROWS;
    const int blk = blockIdx.x;
    const int b    = blk >> 7;
    const int tile = blk & 127;
    const int tz = tile >> 3;
    const int tx = tile & 7;
    const int oz = tz*TZN - HALO, ox = tx*TXN - HALO;
    const int gx = ox + col;
    const int sy = src_y[b], sx = src_x[b];
    const int ph = 2*b;                  // batch phase; CU partners offset by 4

    if (tid == 0) recCnt = 0;
    for (int k = tid; k < 2*2*NWAVE*RXN; k += NTHR) ((float*)bnd)[k] = 0.f;
    for (int k = tid; k < NT; k += NTHR) xs[k] = x[b*NT + k];
    __syncthreads();
    for (int r = tid; r < NREC; r += NTHR) {
        int ry = rec_y[r], rx = rec_x[r];
        if (ry/TZN == tz && rx/TXN == tx) {
            int p = atomicAdd(&recCnt, 1);
            recLoc[p] = ((ry - oz) << 6) | (rx - ox);
            recOut[p] = b*NREC + r;
        }
    }
    __syncthreads();

    int myN = 0, myM[4], myP[4];
    bool ovf = false;
    for (int p = 0; p < recCnt; ++p) {
        int rl = recLoc[p];
        if ((rl & 63) == col) {
            int rm = (rl >> 6) - r0;
            if ((unsigned)rm < (unsigned)ROWS) {
                if (myN < 4) { myM[myN] = rm; myP[myN] = p; ++myN; }
                else ovf = true;
            }
        }
    }
    const bool waveRec = __any(myN > 0 || ovf);

    int nbId = blk;
    if (tid < 8) {
        int d = tid + (tid >= 4);
        int nz2 = tz + d/3 - 1, nx2 = tx + d%3 - 1;
        if ((unsigned)nz2 < (unsigned)NTBZ && (unsigned)nx2 < (unsigned)NTBX)
            nbId = (b << 7) | (nz2 << 3) | nx2;
    }

    float cur[ROWS], prv[ROWS], c2i[ROWS];
    #pragma unroll
    for (int m = 0; m < ROWS; ++m) {
        cur[m] = 0.f; prv[m] = 0.f;
        const int gz = oz + r0 + m;
        const bool inner = (gz > 0 && gz < NZ-1 && gx > 0 && gx < NX-1);
        const float v = inner ? vp[gz*NX + gx] * DT : 0.f;
        c2i[m] = v * v * INV_DH2;    // 0 at edges -> lap auto-masked
    }
    const bool srcCol = (gx == sx);
    const int  srcM   = sy - oz - r0;
    const int  iuUp   = (2*w-1 < 0) ? 0 : 2*w-1;
    const int  iuDn   = (2*w+2 > 2*NWAVE-1) ? 2*NWAVE-1 : 2*w+2;
    const bool gxIn   = (gx >= 0 && gx < NX);
    const int  gxc    = min(max(gx, 0), NX-1);
    int oCnt = 0;
    __syncthreads();

    #pragma unroll 1
    for (int t = 0; t < NT; ++t) {
        const int p  = (t + ph) & 7;    // phase within this batch's window
        const int pr = t & 1, pw = pr ^ 1;
        const float upB = bnd[pr][iuUp][col];
        const float dnB = bnd[pr][iuDn][col];

        // unconditional stencil + update: garbage from region edges penetrates
        // 1 cell/step, <= HALO per window -> frame band [8,RZN-8) stays exact
        float hn[ROWS];
        #pragma unroll
        for (int m = 0; m < ROWS; ++m) {
            const float ce = cur[m];
            const float up = (m == 0) ? upB : cur[m-1];
            const float dn = (m == ROWS-1) ? dnB : cur[m+1];
            const float lf = dpp_shl1(ce);
            const float rt = dpp_shr1(ce);
            const float sm = (up + dn) + (lf + rt);
            hn[m] = fmaf(2.f, ce, -prv[m]) + c2i[m] * fmaf(-4.f, ce, sm);
        }
        #pragma unroll
        for (int m = 0; m < ROWS; ++m) { prv[m] = cur[m]; cur[m] = hn[m]; }

        if (srcCol && (unsigned)srcM < (unsigned)ROWS) {
            const float xv = xs[t];
            #pragma unroll
            for (int m = 0; m < ROWS; ++m) if (m == srcM) cur[m] += xv;
        }
        if (waveRec) {
            if (ovf) {
                for (int q = 0; q < recCnt; ++q) {
                    int rl = recLoc[q];
                    if ((rl & 63) == col) {
                        int rm = (rl >> 6) - r0;
                        if ((unsigned)rm < (unsigned)ROWS) {
                            float v = cur[0];
                            #pragma unroll
                            for (int m = 1; m < ROWS; ++m) if (rm == m) v = cur[m];
                            recBuf[q][p] = v;
                        }
                    }
                }
            } else {
                #pragma unroll
                for (int k = 0; k < 4; ++k) {
                    if (k < myN) {
                        float v = cur[0];
                        #pragma unroll
                        for (int m = 1; m < ROWS; ++m) if (myM[k] == m) v = cur[m];
                        recBuf[myP[k]][p] = v;
                    }
                }
            }
        }
        bnd[pw][2*w  ][col] = cur[0];
        bnd[pw][2*w+1][col] = cur[ROWS-1];

        if (t == NT-1) {
            __syncthreads();
            for (int k = tid; k < recCnt*8; k += NTHR) {
                int q = k >> 3, s2 = k & 7;
                if (s2 <= p) {
                    int tg = t - p + s2;
                    y[(size_t)tg*(BB*NREC) + recOut[q]] = recBuf[q][s2];
                }
            }
        } else if (p == 7) {
            // ---- window exchange (phase-shifted per batch) ----
            float* Gc = (oCnt & 1) ? F1 : F0;
            float* Gp = Gc + BNZX;
            const bool colF = (col >= HALO   && col < RXN-HALO);
            const bool colM = (col >= 2*HALO && col < RXN-2*HALO);
            #pragma unroll
            for (int m = 0; m < ROWS; ++m) {
                const int i = r0 + m;
                const bool rowF = (i >= HALO   && i < RZN-HALO);
                const bool rowM = (i >= 2*HALO && i < RZN-2*HALO);
                if (colF && rowF && !(colM && rowM)) {
                    const size_t g = (size_t)b*NZX + (size_t)(oz+i)*NX + gx;
                    stgf(&Gc[g], cur[m]);
                    stgf(&Gp[g], prv[m]);
                }
            }
            __syncthreads();  // per-wave vmcnt(0) drains + recBuf visible
            if (tid < 64) {   // wave 0: arrive + hard-spin on <=8 neighbors
                if (tid == 0)
                    __hip_atomic_store(&flags[blk * FSTRIDE], (unsigned)(oCnt+1),
                                       __ATOMIC_RELAXED, __HIP_MEMORY_SCOPE_AGENT);
                for (;;) {
                    unsigned f = ldflag(&flags[nbId * FSTRIDE]);
                    if (__all(f >= (unsigned)(oCnt+1))) break;
                }
            } else {          // waves 1..3: flush y concurrently with the poll
                for (int k = tid - 64; k < recCnt*8; k += NTHR - 64) {
                    int q = k >> 3, s2 = k & 7;
                    int tg = t - 7 + s2;
                    if (tg >= 0)
                        y[(size_t)tg*(BB*NREC) + recOut[q]] = recBuf[q][s2];
                }
            }
            __syncthreads();
            // ring reload: issue ALL loads, then use (single waitcnt)
            const bool colH = (col < HALO || col >= RXN-HALO);
            float tc[ROWS], tp[ROWS];
            bool ringm[ROWS], valm[ROWS];
            #pragma unroll
            for (int m = 0; m < ROWS; ++m) {
                const int i = r0 + m;
                const int gz = oz + i;
                ringm[m] = colH || i < HALO || i >= RZN-HALO;
                valm[m]  = gxIn && gz >= 0 && gz < NZ;
                const int gzc = min(max(gz, 0), NZ-1);
                if (ringm[m]) {
                    const size_t g = (size_t)b*NZX + (size_t)gzc*NX + gxc;
                    tc[m] = ldgf(&Gc[g]);
                    tp[m] = ldgf(&Gp[g]);
                }
            }
            #pragma unroll
            for (int m = 0; m < ROWS; ++m) {
                if (ringm[m]) {
                    cur[m] = valm[m] ? tc[m] : 0.f;
                    prv[m] = valm[m] ? tp[m] : 0.f;
                }
            }
            bnd[pw][2*w  ][col] = cur[0];
            bnd[pw][2*w+1][col] = cur[ROWS-1];
            ++oCnt;
        }
        __syncthreads();
    }
}

extern "C" void kernel_launch(void* const* d_in, const int* in_sizes, int n_in,
                              void* d_out, int out_size, void* d_ws, size_t ws_size,
                              hipStream_t stream) {
    const float* x     = (const float*)d_in[0];
    const float* vp    = (const float*)d_in[1];
    const int*   src_y = (const int*)d_in[2];
    const int*   src_x = (const int*)d_in[3];
    const int*   rec_y = (const int*)d_in[4];
    const int*   rec_x = (const int*)d_in[5];
    float* y  = (float*)d_out;
    float* ws = (float*)d_ws;   // 4*BNZX frame floats + 512*16 flag words (~9.5 MB)

    wave_init<<<(NBLK*FSTRIDE + 255)/256, 256, 0, stream>>>((unsigned*)(ws + 4*BNZX));
    wave_tiled<<<NBLK, NTHR, 0, stream>>>(ws, vp, x, src_y, src_x, rec_y, rec_x, y);
}